// Round 9
// baseline (187.233 us; speedup 1.0000x reference)
//
#include <hip/hip_runtime.h>

// B=4, T=2048, C=1024, H=16, D=64. SCALE = 1/8.
// Workspace layout (bytes), total 92,274,688 (~88 MB):
//   xb     @ 0         : bf16 [8192][1024]   (tflags int[64] reuses ws+0 AFTER qkv gemm)
//   WqkvT  @ 16777216  : bf16 [3072][1024]
//   WprojT @ 23068672  : bf16 [1024][1024]
//   Q      @ 25165824  : bf16 [64][2048][64]   (pre-scaled by SCALE*log2e)
//   K      @ 41943040  : bf16 [64][2048][64]
//   VT     @ 58720256  : bf16 [64][64][2048]
//   AO     @ 75497472  : bf16 [8192][1024]

typedef __bf16 bf16;
typedef __bf16 bf16x4 __attribute__((ext_vector_type(4)));
typedef __bf16 bf16x8 __attribute__((ext_vector_type(8)));
typedef float f32x4 __attribute__((ext_vector_type(4)));

#define MFMA(a, b, c) __builtin_amdgcn_mfma_f32_16x16x32_bf16((a), (b), (c), 0, 0, 0)

typedef const __attribute__((address_space(1))) void* gas_ptr;
typedef __attribute__((address_space(3))) void* las_ptr;

__device__ __forceinline__ void gload_lds16(const bf16* g, bf16* lds) {
  __builtin_amdgcn_global_load_lds((gas_ptr)g, (las_ptr)lds, 16, 0, 0);
}

// ---------------- elementwise f32 -> bf16 ----------------
__global__ __launch_bounds__(256) void k_cvt(const float* __restrict__ src,
                                             bf16* __restrict__ dst, int n4) {
  int i = blockIdx.x * 256 + threadIdx.x;
  if (i >= n4) return;
  float4 v = ((const float4*)src)[i];
  bf16x4 o = { (bf16)v.x, (bf16)v.y, (bf16)v.z, (bf16)v.w };
  ((bf16x4*)dst)[i] = o;
}

// ---------------- transpose f32 [R][C] -> bf16 [C][R] ----------------
__global__ __launch_bounds__(256) void k_transpose(const float* __restrict__ src,
                                                   bf16* __restrict__ dst,
                                                   int R, int C) {
  __shared__ float tile[32][33];
  int c0 = blockIdx.x * 32, r0 = blockIdx.y * 32;
  int x = threadIdx.x & 31, y = threadIdx.x >> 5;  // 32 x 8
#pragma unroll
  for (int i = 0; i < 4; ++i)
    tile[y + i * 8][x] = src[(size_t)(r0 + y + i * 8) * C + (c0 + x)];
  __syncthreads();
#pragma unroll
  for (int i = 0; i < 4; ++i)
    dst[(size_t)(c0 + y + i * 8) * R + (r0 + x)] = (bf16)tile[x][y + i * 8];
}

// ---------------- per-(b,kv-tile-128) padding-mask flags ----------------
__global__ void k_maskflags(const unsigned char* __restrict__ kpm,
                            int* __restrict__ flags) {
  int i = threadIdx.x;  // 64 threads: i = b*16 + kvtile
  const uint4* p = (const uint4*)(kpm + i * 128);
  unsigned acc = 0;
#pragma unroll
  for (int j = 0; j < 8; ++j) { uint4 v = p[j]; acc |= v.x | v.y | v.z | v.w; }
  flags[i] = (acc != 0) ? 1 : 0;
}

// ---------------- 128x128 bf16 GEMM, B^T input ----------------
// EPI 0: qkv epilogue (bias + scatter to Q(prescaled)/K/VT bf16)
// EPI 1: proj epilogue (bias + fp32 out)
template <int EPI>
__global__ __launch_bounds__(256, 2)
void k_gemm_bt(const bf16* __restrict__ A, const bf16* __restrict__ Bt,
               const float* __restrict__ bias, float* __restrict__ fout,
               bf16* __restrict__ qp, bf16* __restrict__ kp,
               bf16* __restrict__ vtp, int M, int N, int K) {
  __shared__ bf16 Ab[2][128 * 32];
  __shared__ bf16 Bb[2][128 * 32];
  const int tid = threadIdx.x;
  const int wave = tid >> 6, lane = tid & 63;
  const int m0 = blockIdx.x * 128, n0 = blockIdx.y * 128;
  const int wr = wave >> 1, wc = wave & 1;  // 2x2 wave grid, 64x64 per wave
  const int lrow = lane & 15, kb = (lane >> 4) * 8;
  f32x4 acc[4][4] = {};
  const int nkt = K >> 5;  // BK = 32

  auto stage = [&](int buf, int kt) {
#pragma unroll
    for (int i = 0; i < 2; ++i) {
      int c = i * 4 + wave;
      const bf16* ga = A + (size_t)(m0 + c * 16 + (lane >> 2)) * K + kt * 32 + (lane & 3) * 8;
      gload_lds16(ga, &Ab[buf][c * 512]);
      const bf16* gb = Bt + (size_t)(n0 + c * 16 + (lane >> 2)) * K + kt * 32 + (lane & 3) * 8;
      gload_lds16(gb, &Bb[buf][c * 512]);
    }
  };

  stage(0, 0);
  asm volatile("s_waitcnt vmcnt(0)" ::: "memory");
  __syncthreads();
  int cur = 0;
  for (int kt = 0; kt < nkt; ++kt) {
    if (kt + 1 < nkt) stage(cur ^ 1, kt + 1);
    bf16x8 af[4], bfr[4];
#pragma unroll
    for (int m = 0; m < 4; ++m)
      af[m] = *(const bf16x8*)&Ab[cur][(wr * 64 + m * 16 + lrow) * 32 + kb];
#pragma unroll
    for (int n = 0; n < 4; ++n)
      bfr[n] = *(const bf16x8*)&Bb[cur][(wc * 64 + n * 16 + lrow) * 32 + kb];
#pragma unroll
    for (int m = 0; m < 4; ++m)
#pragma unroll
      for (int n = 0; n < 4; ++n)
        acc[m][n] = MFMA(af[m], bfr[n], acc[m][n]);
    asm volatile("s_waitcnt vmcnt(0)" ::: "memory");
    __syncthreads();
    cur ^= 1;
  }

#pragma unroll
  for (int m = 0; m < 4; ++m) {
#pragma unroll
    for (int n = 0; n < 4; ++n) {
      const int col = n0 + wc * 64 + n * 16 + lrow;
      const int row0 = m0 + wr * 64 + m * 16 + (lane >> 4) * 4;
      const float bv = bias[col];
      if (EPI == 0) {
        const int which = col >> 10;
        const int h = (col >> 6) & 15, d = col & 63;
        const int b = row0 >> 11, t0 = row0 & 2047;
        const int bh = b * 16 + h;
        if (which == 2) {
          bf16x4 pk;
#pragma unroll
          for (int j = 0; j < 4; ++j) pk[j] = (bf16)(acc[m][n][j] + bv);
          *(bf16x4*)&vtp[((size_t)bh * 64 + d) * 2048 + t0] = pk;
        } else {
          bf16* dstp = (which == 0) ? qp : kp;
          const float sc = (which == 0) ? 0.18033688011112042f : 1.0f;  // SCALE*log2(e)
#pragma unroll
          for (int j = 0; j < 4; ++j)
            dstp[((size_t)bh * 2048 + (t0 + j)) * 64 + d] = (bf16)((acc[m][n][j] + bv) * sc);
        }
      } else {
#pragma unroll
        for (int j = 0; j < 4; ++j)
          fout[(size_t)(row0 + j) * N + col] = acc[m][n][j] + bv;
      }
    }
  }
}

// ---------------- flash attention (fragment-native LDS, ones-MFMA rowsum) ----------------
// Q,K: [64][2048][64] bf16 (Q prescaled by SCALE*log2e); VT: [64][64][2048] bf16; out AO bf16.
// Grid (64, 16): bx = bh (XCD-local), by -> qt = 15-by (largest blocks dispatch first).
// Maxless softmax: P = exp2(s) raw; shift cancels in O = (P V)/sum(P).
// K/V staged fragment-native: gload_lds16 dest is base+lane*16, which IS the MFMA
// fragment layout -> all K/V ds_reads are contiguous 1KB b128, zero addr math.
__global__ __launch_bounds__(256, 3)
void k_flash(const bf16* __restrict__ Q, const bf16* __restrict__ Kg,
             const bf16* __restrict__ Vt, const unsigned char* __restrict__ kpm,
             const int* __restrict__ tflags, bf16* __restrict__ O) {
  const int bh = blockIdx.x;  // 0..63
  const int b = bh >> 4, h = bh & 15;
  const int qt = 15 - (int)blockIdx.y;
  const int tid = threadIdx.x, wave = tid >> 6, lane = tid & 63;
  const int lrow = lane & 15, g = lane >> 4;

  __shared__ bf16 Kt[16 * 512];   // 16KB: chunk(n,ks)=n*2+ks; lane*8 holds K[n*16+lrow][ks*32+g*8]
  __shared__ bf16 Vts[16 * 512];  // 16KB: chunk(ks,nt)=ks*4+nt; lane*8 holds VT[nt*16+lrow][ks*32+g*8]
  __shared__ bf16 PT[4][2048];    // per wave 4KB: PT[kv=128][q=16], reused across m

  const bf16* Kbh = Kg + (size_t)bh * 2048 * 64;
  const bf16* Vbh = Vt + (size_t)bh * 64 * 2048;

  // tr-read base: group g gathers PT rows kv0=ks*32+g*8..+3 (lo) / +4..+7 (hi, +128B)
  const int ptb2 = g * 256 + lrow * 8;

  const bf16* Qbase = Q + ((size_t)bh * 2048 + qt * 128 + wave * 32) * 64;
  bf16x8 qf[2][2];
#pragma unroll
  for (int m = 0; m < 2; ++m)
#pragma unroll
    for (int ks = 0; ks < 2; ++ks)
      qf[m][ks] = *(const bf16x8*)&Qbase[(m * 16 + lrow) * 64 + ks * 32 + g * 8];

  const bf16 one_bf = (bf16)1.0f;
  const bf16x8 ones8 = { one_bf, one_bf, one_bf, one_bf, one_bf, one_bf, one_bf, one_bf };

  f32x4 oacc[2][4] = {};
  f32x4 osum[2] = {};  // row-sum accumulator via ones-MFMA; osum[m][j] = sum P[row g*4+j]

  for (int kvt = 0; kvt <= qt; ++kvt) {
    // ---- stage K, V fragment-native (per-lane source; linear LDS dest) ----
#pragma unroll
    for (int i = 0; i < 4; ++i) {
      int c = i * 4 + wave;  // K chunk: n=c>>1, ks=c&1
      gload_lds16(Kbh + (size_t)(kvt * 128 + (c >> 1) * 16 + lrow) * 64 + (c & 1) * 32 + g * 8,
                  &Kt[c * 512]);
    }
#pragma unroll
    for (int i = 0; i < 4; ++i) {
      int c = i * 4 + wave;  // V chunk: ks=c>>2, nt=c&3
      gload_lds16(Vbh + (size_t)((c & 3) * 16 + lrow) * 2048 + kvt * 128 + (c >> 2) * 32 + g * 8,
                  &Vts[c * 512]);
    }
    asm volatile("s_waitcnt vmcnt(0)" ::: "memory");
    __builtin_amdgcn_s_barrier();
    __builtin_amdgcn_sched_barrier(0);

    const bool diag = (kvt == qt);
    const int nmax = diag ? (2 * wave + 2) : 8;   // causal trim per wave
    const int ksmax = diag ? (wave + 1) : 4;

    // ---- S = Q K^T (linear fragment reads) ----
    f32x4 s[2][8];
    __builtin_amdgcn_s_setprio(1);
#pragma unroll
    for (int n = 0; n < 8; ++n) {
      if (n < nmax) {
        bf16x8 kf0 = *(const bf16x8*)&Kt[(n * 2 + 0) * 512 + lane * 8];
        bf16x8 kf1 = *(const bf16x8*)&Kt[(n * 2 + 1) * 512 + lane * 8];
#pragma unroll
        for (int m = 0; m < 2; ++m) {
          f32x4 t = {};
          t = MFMA(qf[m][0], kf0, t);
          t = MFMA(qf[m][1], kf1, t);
          s[m][n] = t;
        }
      }
    }
    __builtin_amdgcn_s_setprio(0);

    // ---- masking ----
    if (tflags[b * 16 + kvt]) {
#pragma unroll
      for (int n = 0; n < 8; ++n) {
        if (n < nmax) {
          const int col = kvt * 128 + n * 16 + lrow;
          if (kpm[b * 2048 + col]) {
#pragma unroll
            for (int m = 0; m < 2; ++m)
#pragma unroll
              for (int j = 0; j < 4; ++j) s[m][n][j] = -1e30f;
          }
        }
      }
    }
    if (diag) {  // causal within the diagonal tile
#pragma unroll
      for (int n = 0; n < 8; ++n) {
        if (n < nmax) {
          const int ccol = n * 16 + lrow;
#pragma unroll
          for (int m = 0; m < 2; ++m)
#pragma unroll
            for (int j = 0; j < 4; ++j) {
              const int crow = wave * 32 + m * 16 + g * 4 + j;
              if (ccol > crow) s[m][n][j] = -1e30f;
            }
        }
      }
    }

    // ---- maxless softmax + PV, m sequential through the 4KB PT buffer ----
#pragma unroll
    for (int m = 0; m < 2; ++m) {
#pragma unroll
      for (int n = 0; n < 8; ++n) {
        if (n < nmax) {
          bf16x4 pk;
#pragma unroll
          for (int j = 0; j < 4; ++j) pk[j] = (bf16)exp2f(s[m][n][j]);
          const int woff = (n * 16 + lrow) * 32 + g * 8;
          *(bf16x4*)((char*)&PT[wave][0] + woff) = pk;
        }
      }
      asm volatile("s_waitcnt lgkmcnt(0)" ::: "memory");  // PT writes landed (wave-local)
      __builtin_amdgcn_sched_barrier(0);
#pragma unroll
      for (int ks = 0; ks < 4; ++ks) {
        if (ks < ksmax) {
          bf16x4 plo, phi;
          las_ptr pa_ = (las_ptr)((char*)&PT[wave][0] + ptb2);
          asm volatile("ds_read_b64_tr_b16 %0, %1 offset:%2"
                       : "=v"(plo) : "v"(pa_), "i"(ks * 1024));
          asm volatile("ds_read_b64_tr_b16 %0, %1 offset:%2"
                       : "=v"(phi) : "v"(pa_), "i"(ks * 1024 + 128));
          bf16x8 vf[4];
#pragma unroll
          for (int nt = 0; nt < 4; ++nt)
            vf[nt] = *(const bf16x8*)&Vts[(ks * 4 + nt) * 512 + lane * 8];
          asm volatile("s_waitcnt lgkmcnt(0)" ::: "memory");
          __builtin_amdgcn_sched_barrier(0);
          bf16x8 pa = __builtin_shufflevector(plo, phi, 0, 1, 2, 3, 4, 5, 6, 7);
          __builtin_amdgcn_s_setprio(1);
#pragma unroll
          for (int nt = 0; nt < 4; ++nt)
            oacc[m][nt] = MFMA(pa, vf[nt], oacc[m][nt]);
          osum[m] = MFMA(pa, ones8, osum[m]);  // row-sum: D[q][c] = sum_k P[q][k]
          __builtin_amdgcn_s_setprio(0);
        }
      }
    }  // m

    __builtin_amdgcn_s_barrier();  // compute done before next stage overwrites Kt/Vts
    __builtin_amdgcn_sched_barrier(0);
  }  // kvt

  // ---- epilogue (osum already holds full row sums; no reduce needed) ----
#pragma unroll
  for (int m = 0; m < 2; ++m)
#pragma unroll
    for (int nt = 0; nt < 4; ++nt)
#pragma unroll
      for (int j = 0; j < 4; ++j) {
        const int t = qt * 128 + wave * 32 + m * 16 + g * 4 + j;
        const int c = h * 64 + nt * 16 + lrow;
        O[((size_t)b * 2048 + t) * 1024 + c] = (bf16)(oacc[m][nt][j] / osum[m][j]);
      }
}

extern "C" void kernel_launch(void* const* d_in, const int* in_sizes, int n_in,
                              void* d_out, int out_size, void* d_ws, size_t ws_size,
                              hipStream_t stream) {
  const float* x = (const float*)d_in[0];
  const unsigned char* kpm = (const unsigned char*)d_in[1];
  const float* Wqkv = (const float*)d_in[2];
  const float* bqkv = (const float*)d_in[3];
  const float* Wproj = (const float*)d_in[4];
  const float* bproj = (const float*)d_in[5];
  float* out = (float*)d_out;
  char* ws = (char*)d_ws;

  bf16* xb     = (bf16*)(ws + 0);
  bf16* WqkvT  = (bf16*)(ws + 16777216);
  bf16* WprojT = (bf16*)(ws + 23068672);
  bf16* Qb     = (bf16*)(ws + 25165824);
  bf16* Kb     = (bf16*)(ws + 41943040);
  bf16* Vtb    = (bf16*)(ws + 58720256);
  bf16* AOb    = (bf16*)(ws + 75497472);
  int*  tflags = (int*)(ws + 0);  // reuses xb region AFTER qkv gemm consumed it

  k_cvt<<<8192, 256, 0, stream>>>(x, xb, 2097152);
  k_transpose<<<dim3(96, 32), 256, 0, stream>>>(Wqkv, WqkvT, 1024, 3072);
  k_transpose<<<dim3(32, 32), 256, 0, stream>>>(Wproj, WprojT, 1024, 1024);
  k_gemm_bt<0><<<dim3(64, 24), 256, 0, stream>>>(xb, WqkvT, bqkv, nullptr, Qb, Kb,
                                                 Vtb, 8192, 3072, 1024);
  k_maskflags<<<1, 64, 0, stream>>>(kpm, tflags);
  k_flash<<<dim3(64, 16), 256, 0, stream>>>(Qb, Kb, Vtb, kpm, tflags, AOb);
  k_gemm_bt<1><<<dim3(64, 8), 256, 0, stream>>>(AOb, WprojT, bproj, out, nullptr,
                                                nullptr, nullptr, 8192, 1024, 1024);
}